// Round 18
// baseline (987.350 us; speedup 1.0000x reference)
//
#include <hip/hip_runtime.h>
#include <hip/hip_fp16.h>
#include <cstdint>
#include <cstddef>

// ---------------- helpers ----------------

__device__ __forceinline__ float sigmoidf_(float x) {
    return 1.0f / (1.0f + __expf(-x));
}

template<int OUT>
__device__ __forceinline__ void load_bias(const float* __restrict__ b, float* __restrict__ acc) {
#pragma unroll
    for (int j = 0; j < OUT; ++j) acc[j] = b[j];
}

template<int OUT>
__device__ __forceinline__ void relu_v(float* __restrict__ acc) {
#pragma unroll
    for (int j = 0; j < OUT; ++j) acc[j] = fmaxf(acc[j], 0.0f);
}

template<int IN, int OUT>
__device__ __forceinline__ void mm_acc(const float* __restrict__ x,
                                       const float* __restrict__ W,
                                       float* __restrict__ acc) {
#pragma unroll 4
    for (int k = 0; k < IN; ++k) {
        const float v = x[k];
#pragma unroll
        for (int j = 0; j < OUT; ++j) acc[j] = fmaf(v, W[k * OUT + j], acc[j]);
    }
}

template<int WIDTH>
__device__ __forceinline__ void load_row(const float* __restrict__ p, float* __restrict__ x) {
#pragma unroll
    for (int k4 = 0; k4 < WIDTH / 4; ++k4) {
        float4 v = reinterpret_cast<const float4*>(p)[k4];
        x[k4 * 4 + 0] = v.x; x[k4 * 4 + 1] = v.y;
        x[k4 * 4 + 2] = v.z; x[k4 * 4 + 3] = v.w;
    }
}

template<int PAIRS>
__device__ __forceinline__ void load_h2(const __half2* __restrict__ p, float* __restrict__ x) {
#pragma unroll
    for (int q = 0; q < PAIRS; ++q) {
        const float2 f = __half22float2(p[q]);
        x[2 * q] = f.x; x[2 * q + 1] = f.y;
    }
}

// edge encoder: rbf(16)+raw(2) -> 4 -> 8 (relu after each)
__device__ __forceinline__ void enc_edge(int orig,
                                         const float* __restrict__ dist,
                                         const float* __restrict__ eraw,
                                         const float* __restrict__ We1, const float* __restrict__ be1,
                                         const float* __restrict__ We2, const float* __restrict__ be2,
                                         float* __restrict__ out8) {
    float x[18];
    const float d = dist[orig];
#pragma unroll
    for (int i = 0; i < 16; ++i) {
        const float c = (float)i * (20.0f / 15.0f);
        const float t = d - c;
        x[i] = __expf(-t * t);
    }
    x[16] = eraw[(size_t)orig * 2 + 0];
    x[17] = eraw[(size_t)orig * 2 + 1];
    float h[4];
    load_bias<4>(be1, h);
    mm_acc<18, 4>(x, We1, h);
    relu_v<4>(h);
    load_bias<8>(be2, out8);
    mm_acc<4, 8>(h, We2, out8);
    relu_v<8>(out8);
}

// y-hoisted chain: a0 = relu(y0[s] + enc@We0)
__device__ __forceinline__ void chain_ef0_y(int orig, int s,
    const float* __restrict__ dist, const float* __restrict__ eraw,
    const float* __restrict__ eWe1, const float* __restrict__ ebe1,
    const float* __restrict__ eWe2, const float* __restrict__ ebe2,
    const float* __restrict__ We0,
    const float* __restrict__ y0, float* __restrict__ a0)
{
    load_row<16>(y0 + (size_t)s * 16, a0);   // issue gather early (includes b0)
    float enc[8];
    enc_edge(orig, dist, eraw, eWe1, ebe1, eWe2, ebe2, enc);
    mm_acc<8, 16>(enc, We0, a0);
    relu_v<16>(a0);
}

// old chain for fallback path (verified)
__device__ __forceinline__ void chain_ef0(int orig, int s,
    const float* __restrict__ dist, const float* __restrict__ eraw,
    const float* __restrict__ eWe1, const float* __restrict__ ebe1,
    const float* __restrict__ eWe2, const float* __restrict__ ebe2,
    const float* __restrict__ We0, const float* __restrict__ Ws0, const float* __restrict__ b0,
    const float* __restrict__ nf0, float* __restrict__ a0)
{
    float x0[16];
    load_row<16>(nf0 + (size_t)s * 16, x0);
    float enc[8];
    enc_edge(orig, dist, eraw, eWe1, ebe1, eWe2, ebe2, enc);
    load_bias<16>(b0, a0);
    mm_acc<8, 16>(enc, We0, a0);
    mm_acc<16, 16>(x0, Ws0, a0);
    relu_v<16>(a0);
}

__device__ __forceinline__ int lower_bound_i(const int* __restrict__ a, int n, int key) {
    int lo = 0, hi = n;
    while (lo < hi) {
        int mid = (lo + hi) >> 1;
        if (a[mid] < key) lo = mid + 1; else hi = mid;
    }
    return lo;
}

// first index with a[idx] > key
__device__ __forceinline__ int upper_bound_i(const int* __restrict__ a, int n, int key) {
    int lo = 0, hi = n;
    while (lo < hi) {
        int mid = (lo + hi) >> 1;
        if (a[mid] <= key) lo = mid + 1; else hi = mid;
    }
    return lo;
}

// ---------------- CSR build ----------------

__global__ void __launch_bounds__(256) k_count(
    const int* __restrict__ senders, const int* __restrict__ receivers,
    int* __restrict__ ideg, int E)
{
    const int e = blockIdx.x * blockDim.x + threadIdx.x;
    if (e >= E) return;
    atomicAdd(&ideg[receivers[e]], 1);
    atomicAdd(&ideg[senders[e]], 1);
}

__global__ void __launch_bounds__(256) k_blocksum(
    const int* __restrict__ ideg, int* __restrict__ bsum, int N)
{
    __shared__ int s[256];
    const int t = threadIdx.x;
    const int i = blockIdx.x * 256 + t;
    s[t] = (i < N) ? ideg[i] : 0;
    __syncthreads();
#pragma unroll
    for (int d = 128; d > 0; d >>= 1) {
        if (t < d) s[t] += s[t + d];
        __syncthreads();
    }
    if (t == 0) bsum[blockIdx.x] = s[0];
}

__global__ void __launch_bounds__(1024) k_scan_partials(int* __restrict__ bsum, int nb)
{
    __shared__ int s[1024];
    const int t = threadIdx.x;
    const int v = (t < nb) ? bsum[t] : 0;
    s[t] = v;
    __syncthreads();
    for (int d = 1; d < 1024; d <<= 1) {
        const int w = (t >= d) ? s[t - d] : 0;
        __syncthreads();
        s[t] += w;
        __syncthreads();
    }
    if (t < nb) bsum[t] = s[t] - v;   // exclusive
}

__global__ void __launch_bounds__(256) k_blockscan(
    const int* __restrict__ ideg, const int* __restrict__ bsum,
    int* __restrict__ offs, int* __restrict__ cursor, int N)
{
    __shared__ int s[256];
    const int t = threadIdx.x;
    const int i = blockIdx.x * 256 + t;
    const int v = (i < N) ? ideg[i] : 0;
    s[t] = v;
    __syncthreads();
    for (int d = 1; d < 256; d <<= 1) {
        const int w = (t >= d) ? s[t - d] : 0;
        __syncthreads();
        s[t] += w;
        __syncthreads();
    }
    if (i < N) {
        const int o = bsum[blockIdx.x] + s[t] - v;
        offs[i] = o;
        cursor[i] = o;
    }
}

// packed: slot -> {orig edge, sender node} in one 8B store
__global__ void __launch_bounds__(256) k_scatter(
    const int* __restrict__ senders, const int* __restrict__ receivers,
    int* __restrict__ cursor, int2* __restrict__ perm2, int E)
{
    const int e = blockIdx.x * blockDim.x + threadIdx.x;
    if (e >= E) return;
    const int se = senders[e];
    const int re = receivers[e];
    const int p = atomicAdd(&cursor[re], 1);
    perm2[p] = make_int2(e, se);
    const int q = atomicAdd(&cursor[se], 1);
    perm2[q] = make_int2(e, re);
}

// ---------------- node-side kernels ----------------

__global__ void __launch_bounds__(256) node_enc_kernel(
    const float* __restrict__ node_raw, const int* __restrict__ residues,
    const float* __restrict__ emb,
    const float* __restrict__ Wn1, const float* __restrict__ bn1,
    const float* __restrict__ Wn2, const float* __restrict__ bn2,
    const float* __restrict__ Ws0, const float* __restrict__ b0,
    float* __restrict__ nf0, float* __restrict__ y0, int N)
{
    __shared__ float raw[256 * 51];
    const int t = threadIdx.x;
    const int n0 = blockIdx.x * 256;
    int cnt = N - n0; if (cnt > 256) cnt = 256;
    const int tot = cnt * 51;
    for (int i = t; i < tot; i += 256)
        raw[i] = node_raw[(size_t)n0 * 51 + i];
    __syncthreads();

    const int n = n0 + t;
    if (n >= N) return;
    float h[8];
    load_bias<8>(bn1, h);
    {
        const float* er = emb + (size_t)residues[n] * 32;
        float x[32];
        load_row<32>(er, x);
        mm_acc<32, 8>(x, Wn1, h);
    }
    {
        const float* nr = &raw[t * 51];
#pragma unroll 4
        for (int k = 0; k < 51; ++k) {
            const float v = nr[k];
#pragma unroll
            for (int j = 0; j < 8; ++j) h[j] = fmaf(v, Wn1[(32 + k) * 8 + j], h[j]);
        }
    }
    relu_v<8>(h);
    float o[16];
    load_bias<16>(bn2, o);
    mm_acc<8, 16>(h, Wn2, o);
    relu_v<16>(o);
    float* dst = nf0 + (size_t)n * 16;
#pragma unroll
    for (int j = 0; j < 16; ++j) dst[j] = o[j];
    if (y0) {
        float yr[16];
        load_bias<16>(b0, yr);
        mm_acc<16, 16>(o, Ws0, yr);
        float* yd = y0 + (size_t)n * 16;
#pragma unroll
        for (int j = 0; j < 16; ++j) yd[j] = yr[j];
    }
}

// y[n][j] = b[j] + sum_k nf[n][k]*Ws[k][j] (IN==OUT); fp32 out + optional fp16 copy
template<int IN>
__global__ void __launch_bounds__(256) y_kernel(
    const float* __restrict__ nf, const float* __restrict__ Ws, const float* __restrict__ b,
    float* __restrict__ y, __half* __restrict__ yh, int N)
{
    constexpr int BN = 64;
    __shared__ float xs[BN * IN];
    const int t = threadIdx.x;
    const int n0 = blockIdx.x * BN;
    int cnt = N - n0; if (cnt > BN) cnt = BN;
    if (cnt <= 0) return;
    {
        const float4* gx = reinterpret_cast<const float4*>(nf + (size_t)n0 * IN);
        float4* lx = reinterpret_cast<float4*>(xs);
        const int nx = cnt * IN / 4;
        for (int i = t; i < nx; i += 256) lx[i] = gx[i];
    }
    __syncthreads();

    constexpr int SUB = 256 / IN;
    const int j = t % IN;
    const int m = t / IN;
    float w[IN];
#pragma unroll
    for (int k = 0; k < IN; ++k) w[k] = Ws[k * IN + j];
    const float bj = b[j];

    for (int nl = m; nl < cnt; nl += SUB) {
        const float4* x4 = reinterpret_cast<const float4*>(&xs[nl * IN]);
        float p0 = bj, p1 = 0.0f, p2 = 0.0f, p3 = 0.0f;
#pragma unroll
        for (int k4 = 0; k4 < IN / 4; ++k4) {
            float4 v = x4[k4];
            p0 = fmaf(v.x, w[4 * k4 + 0], p0);
            p1 = fmaf(v.y, w[4 * k4 + 1], p1);
            p2 = fmaf(v.z, w[4 * k4 + 2], p2);
            p3 = fmaf(v.w, w[4 * k4 + 3], p3);
        }
        const float r = (p0 + p1) + (p2 + p3);
        if (y)  y[(size_t)(n0 + nl) * IN + j] = r;
        if (yh) yh[(size_t)(n0 + nl) * IN + j] = __float2half(r);
    }
}

// LDS-tiled node layer (small)
template<int INN, int OE, int ON>
__global__ void __launch_bounds__(256) node_layer_v4(
    const float* __restrict__ nf_in, const float* __restrict__ agg, const int* __restrict__ ideg,
    const float* __restrict__ Wn, const float* __restrict__ Wi, const float* __restrict__ bn,
    float* __restrict__ nf_out, int N)
{
    constexpr int BN = 64;
    __shared__ float xs[BN * INN];
    __shared__ float as_[BN * OE];
    __shared__ float inv_s[BN];
    const int t = threadIdx.x;
    const int n0 = blockIdx.x * BN;
    int cnt = N - n0; if (cnt > BN) cnt = BN;
    if (cnt <= 0) return;

    {
        const float4* gx = reinterpret_cast<const float4*>(nf_in + (size_t)n0 * INN);
        float4* lx = reinterpret_cast<float4*>(xs);
        const int nx = cnt * INN / 4;
        for (int i = t; i < nx; i += 256) lx[i] = gx[i];
        const float4* ga = reinterpret_cast<const float4*>(agg + (size_t)n0 * OE);
        float4* la = reinterpret_cast<float4*>(as_);
        const int na = cnt * OE / 4;
        for (int i = t; i < na; i += 256) la[i] = ga[i];
        if (t < cnt) inv_s[t] = 1.0f / fmaxf((float)ideg[n0 + t], 1.0f);
    }
    __syncthreads();

    constexpr int SUB = 256 / ON;
    const int j = t % ON;
    const int m = t / ON;

    float wn[INN], wi[OE];
#pragma unroll
    for (int k = 0; k < INN; ++k) wn[k] = Wn[k * ON + j];
#pragma unroll
    for (int k = 0; k < OE; ++k)  wi[k] = Wi[k * ON + j];
    const float bj = bn[j];

    for (int nl = m; nl < cnt; nl += SUB) {
        const float4* x4 = reinterpret_cast<const float4*>(&xs[nl * INN]);
        const float4* a4 = reinterpret_cast<const float4*>(&as_[nl * OE]);
        const float inv = inv_s[nl];

        float p0 = bj, p1 = 0.0f, p2 = 0.0f, p3 = 0.0f;
#pragma unroll
        for (int k4 = 0; k4 < INN / 4; ++k4) {
            float4 v = x4[k4];
            p0 = fmaf(v.x, wn[4 * k4 + 0], p0);
            p1 = fmaf(v.y, wn[4 * k4 + 1], p1);
            p2 = fmaf(v.z, wn[4 * k4 + 2], p2);
            p3 = fmaf(v.w, wn[4 * k4 + 3], p3);
        }
        float q0 = 0.0f, q1 = 0.0f, q2 = 0.0f, q3 = 0.0f;
#pragma unroll
        for (int k4 = 0; k4 < OE / 4; ++k4) {
            float4 v = a4[k4];
            q0 = fmaf(v.x, wi[4 * k4 + 0], q0);
            q1 = fmaf(v.y, wi[4 * k4 + 1], q1);
            q2 = fmaf(v.z, wi[4 * k4 + 2], q2);
            q3 = fmaf(v.w, wi[4 * k4 + 3], q3);
        }
        const float r = (p0 + p1) + (p2 + p3) + inv * ((q0 + q1) + (q2 + q3));
        nf_out[(size_t)(n0 + nl) * ON + j] = fmaxf(r, 0.0f);
    }
}

// LDS-tiled split-k node layer for 64->128
__global__ void __launch_bounds__(256) node_layer_v4b(
    const float* __restrict__ nf_in, const float* __restrict__ agg, const int* __restrict__ ideg,
    const float* __restrict__ Wn, const float* __restrict__ Wi, const float* __restrict__ bn,
    float* __restrict__ nf_out, int N)
{
    constexpr int BN = 64;
    __shared__ float xs[BN * 64];
    __shared__ float as_[BN * 64];
    __shared__ float inv_s[BN];
    const int t = threadIdx.x;
    const int n0 = blockIdx.x * BN;
    int cnt = N - n0; if (cnt > BN) cnt = BN;
    if (cnt <= 0) return;

    {
        const float4* gx = reinterpret_cast<const float4*>(nf_in + (size_t)n0 * 64);
        float4* lx = reinterpret_cast<float4*>(xs);
        const int nx = cnt * 16;
        for (int i = t; i < nx; i += 256) lx[i] = gx[i];
        const float4* ga = reinterpret_cast<const float4*>(agg + (size_t)n0 * 64);
        float4* la = reinterpret_cast<float4*>(as_);
        for (int i = t; i < nx; i += 256) la[i] = ga[i];
        if (t < cnt) inv_s[t] = 1.0f / fmaxf((float)ideg[n0 + t], 1.0f);
    }
    __syncthreads();

    const int j = t >> 1;
    const int h = t & 1;

    float wn[32], wi[32];
#pragma unroll
    for (int k = 0; k < 32; ++k) wn[k] = Wn[(h * 32 + k) * 128 + j];
#pragma unroll
    for (int k = 0; k < 32; ++k) wi[k] = Wi[(h * 32 + k) * 128 + j];
    const float bj = bn[j];

    for (int nl = 0; nl < cnt; ++nl) {
        const float4* x4 = reinterpret_cast<const float4*>(&xs[nl * 64 + h * 32]);
        const float4* a4 = reinterpret_cast<const float4*>(&as_[nl * 64 + h * 32]);

        float p0 = 0.0f, p1 = 0.0f, p2 = 0.0f, p3 = 0.0f;
#pragma unroll
        for (int k4 = 0; k4 < 8; ++k4) {
            float4 v = x4[k4];
            p0 = fmaf(v.x, wn[4 * k4 + 0], p0);
            p1 = fmaf(v.y, wn[4 * k4 + 1], p1);
            p2 = fmaf(v.z, wn[4 * k4 + 2], p2);
            p3 = fmaf(v.w, wn[4 * k4 + 3], p3);
        }
        float q0 = 0.0f, q1 = 0.0f, q2 = 0.0f, q3 = 0.0f;
#pragma unroll
        for (int k4 = 0; k4 < 8; ++k4) {
            float4 v = a4[k4];
            q0 = fmaf(v.x, wi[4 * k4 + 0], q0);
            q1 = fmaf(v.y, wi[4 * k4 + 1], q1);
            q2 = fmaf(v.z, wi[4 * k4 + 2], q2);
            q3 = fmaf(v.w, wi[4 * k4 + 3], q3);
        }
        float r = (p0 + p1) + (p2 + p3) + inv_s[nl] * ((q0 + q1) + (q2 + q3));
        r += __shfl_xor(r, 1);
        if (h == 0)
            nf_out[(size_t)(n0 + nl) * 128 + j] = fmaxf(r + bj, 0.0f);
    }
}

__global__ void __launch_bounds__(256) node_out_kernel(
    const float* __restrict__ nf3,
    const float* __restrict__ roWn, const float* __restrict__ robn,
    float* __restrict__ node_out, int N)
{
    const int n = blockIdx.x * blockDim.x + threadIdx.x;
    if (n >= N) return;
    const float* x = nf3 + (size_t)n * 128;
    float a0 = robn[0], a1 = robn[1];
#pragma unroll 4
    for (int k4 = 0; k4 < 32; ++k4) {
        float4 v = reinterpret_cast<const float4*>(x)[k4];
        const float vv[4] = {v.x, v.y, v.z, v.w};
#pragma unroll
        for (int u = 0; u < 4; ++u) {
            const int k = k4 * 4 + u;
            a0 = fmaf(vv[u], roWn[k * 2 + 0], a0);
            a1 = fmaf(vv[u], roWn[k * 2 + 1], a1);
        }
    }
    node_out[(size_t)n * 2 + 0] = sigmoidf_(a0);
    node_out[(size_t)n * 2 + 1] = sigmoidf_(a1);
}

__global__ void __launch_bounds__(256) graph_out_kernel(
    const float* __restrict__ nf3, const int* __restrict__ gidx,
    const float* __restrict__ roWg, const float* __restrict__ robg,
    float* __restrict__ glob_out, int N)
{
    __shared__ float sred[256];
    __shared__ float gm[128];
    const int g = blockIdx.x;
    const int t = threadIdx.x;
    const int lo = lower_bound_i(gidx, N, g);
    const int hi = lower_bound_i(gidx, N, g + 1);
    const int cnt = hi - lo;

    const int c = t & 127;
    const int h = t >> 7;
    float acc = 0.0f;
    for (int i = lo + h; i < hi; i += 2)
        acc += nf3[(size_t)i * 128 + c];
    sred[t] = acc;
    __syncthreads();
    if (t < 128) {
        const float m = (sred[t] + sred[t + 128]) / fmaxf((float)cnt, 1.0f);
        gm[t] = m * roWg[t];
    }
    __syncthreads();
    if (t < 64) gm[t] += gm[t + 64];
    __syncthreads();
    if (t < 32) gm[t] += gm[t + 32];
    __syncthreads();
    if (t < 16) gm[t] += gm[t + 16];
    __syncthreads();
    if (t == 0) {
        float s = 0.0f;
#pragma unroll
        for (int i = 0; i < 16; ++i) s += gm[i];
        glob_out[g] = sigmoidf_(s + robg[0]);
    }
}

// ---------------- fused edge-transform + segmented aggregation ----------------

// layer 0: ef0[16], LDS row stride 17 (conflict-free). Optionally stages
// ef0 to global as fp16 (slot-linear, coalesced) for layers 1/2 reuse.
__global__ void __launch_bounds__(256) fused0_kernel(
    const float* __restrict__ dist, const float* __restrict__ eraw,
    const int2* __restrict__ perm2, const float* __restrict__ y0,
    const float* __restrict__ eWe1, const float* __restrict__ ebe1,
    const float* __restrict__ eWe2, const float* __restrict__ ebe2,
    const float* __restrict__ We0,
    const int* __restrict__ offs, const int* __restrict__ ideg,
    float* __restrict__ agg, __half2* __restrict__ ef0h, int N, int E2)
{
    __shared__ float lds[256 * 17];
    const int t = threadIdx.x;
    const int p0 = blockIdx.x * 256;
    int cnt = E2 - p0; if (cnt > 256) cnt = 256;

    if (t < cnt) {
        const int2 pr = perm2[p0 + t];
        float a0[16];
        chain_ef0_y(pr.x, pr.y, dist, eraw, eWe1, ebe1, eWe2, ebe2, We0, y0, a0);
        float* row = &lds[t * 17];
#pragma unroll
        for (int j = 0; j < 16; ++j) row[j] = a0[j];
        if (ef0h) {
            __half2* eh = ef0h + (size_t)(p0 + t) * 8;
#pragma unroll
            for (int q = 0; q < 8; ++q)
                eh[q] = __floats2half2_rn(a0[2 * q], a0[2 * q + 1]);
        }
    }
    __syncthreads();

    const int n_lo = upper_bound_i(offs, N, p0) - 1;
    const int n_hi = upper_bound_i(offs, N, p0 + cnt - 1) - 1;
    const int col = t & 15;
    const int grp = t >> 4;          // 16 groups
    const int pend = p0 + cnt;

    for (int n = n_lo + grp; n <= n_hi; n += 16) {
        int lo = offs[n];
        int hi = lo + ideg[n];
        lo = lo > p0 ? lo : p0;
        hi = hi < pend ? hi : pend;
        if (lo >= hi) continue;
        float acc = 0.0f;
        for (int p = lo; p < hi; ++p)
            acc += lds[(p - p0) * 17 + col];
        atomicAdd(&agg[(size_t)n * 16 + col], acc);
    }
}

// layer 1: ef1[32], stride-32 XOR swizzle. a0 from ef0h (linear fp16) when
// available, else chain recompute. y1 gathered as fp16.
__global__ void __launch_bounds__(256) fused1_kernel(
    const float* __restrict__ dist, const float* __restrict__ eraw,
    const int2* __restrict__ perm2,
    const float* __restrict__ y0, const __half2* __restrict__ y1h,
    const __half2* __restrict__ ef0h,
    const float* __restrict__ eWe1, const float* __restrict__ ebe1,
    const float* __restrict__ eWe2, const float* __restrict__ ebe2,
    const float* __restrict__ We0, const float* __restrict__ We1,
    const int* __restrict__ offs, const int* __restrict__ ideg,
    float* __restrict__ agg, int N, int E2)
{
    __shared__ float lds[256 * 32];   // 32 KB
    const int t = threadIdx.x;
    const int p0 = blockIdx.x * 256;
    int cnt = E2 - p0; if (cnt > 256) cnt = 256;

    if (t < cnt) {
        const int2 pr = perm2[p0 + t];
        const int s = pr.y;
        float a1[32];
        load_h2<16>(y1h + (size_t)s * 16, a1);     // 64 B gather (includes b1)
        float a0[16];
        if (ef0h) {
            load_h2<8>(ef0h + (size_t)(p0 + t) * 8, a0);   // linear 16 B
        } else {
            chain_ef0_y(pr.x, s, dist, eraw, eWe1, ebe1, eWe2, ebe2, We0, y0, a0);
        }
        mm_acc<16, 32>(a0, We1, a1);
        relu_v<32>(a1);
        const int m = t & 31;
        float* row = &lds[t * 32];
#pragma unroll
        for (int j = 0; j < 32; ++j) row[j ^ m] = a1[j];
    }
    __syncthreads();

    const int n_lo = upper_bound_i(offs, N, p0) - 1;
    const int n_hi = upper_bound_i(offs, N, p0 + cnt - 1) - 1;
    const int col = t & 31;
    const int grp = t >> 5;          // 8 groups
    const int pend = p0 + cnt;

    for (int n = n_lo + grp; n <= n_hi; n += 8) {
        int lo = offs[n];
        int hi = lo + ideg[n];
        lo = lo > p0 ? lo : p0;
        hi = hi < pend ? hi : pend;
        if (lo >= hi) continue;
        float acc = 0.0f;
        for (int p = lo; p < hi; ++p) {
            const int sl = p - p0;
            acc += lds[sl * 32 + (col ^ (sl & 31))];
        }
        atomicAdd(&agg[(size_t)n * 32 + col], acc);
    }
}

// layer 2: a0 from ef0h (linear) or chain; y1h/y2h fp16 gathers; ef2 in LDS
// fp16 pair-XOR swizzled. Phase B segmented sum.
__global__ void __launch_bounds__(256) fused2_kernel(
    const float* __restrict__ dist, const float* __restrict__ eraw,
    const int2* __restrict__ perm2,
    const float* __restrict__ y0, const __half2* __restrict__ y1h, const __half2* __restrict__ y2h,
    const __half2* __restrict__ ef0h,
    const float* __restrict__ eWe1, const float* __restrict__ ebe1,
    const float* __restrict__ eWe2, const float* __restrict__ ebe2,
    const float* __restrict__ We0, const float* __restrict__ We1, const float* __restrict__ We2,
    const int* __restrict__ offs, const int* __restrict__ ideg,
    float* __restrict__ agg, int N, int E2)
{
    __shared__ __half2 lds[256 * 32];   // 32 KB, 32 half2 words per slot
    const int t = threadIdx.x;
    const int p0 = blockIdx.x * 256;
    int cnt = E2 - p0; if (cnt > 256) cnt = 256;

    if (t < cnt) {
        const int2 pr = perm2[p0 + t];
        const int s = pr.y;
        // issue long-latency gathers first
        float a2[64];
        load_h2<32>(y2h + (size_t)s * 32, a2);     // 128 B gather (includes b2)
        float a1[32];
        load_h2<16>(y1h + (size_t)s * 16, a1);     // 64 B gather (includes b1)
        float a0[16];
        if (ef0h) {
            load_h2<8>(ef0h + (size_t)(p0 + t) * 8, a0);   // linear 16 B
        } else {
            chain_ef0_y(pr.x, s, dist, eraw, eWe1, ebe1, eWe2, ebe2, We0, y0, a0);
        }
        mm_acc<16, 32>(a0, We1, a1);
        relu_v<32>(a1);
        mm_acc<32, 64>(a1, We2, a2);                 // wave-uniform scalar We2
        const int m = t & 31;
        __half2* row = &lds[t * 32];
#pragma unroll
        for (int q = 0; q < 32; ++q) {
            row[q ^ m] = __floats2half2_rn(fmaxf(a2[2 * q], 0.0f),
                                           fmaxf(a2[2 * q + 1], 0.0f));
        }
    }
    __syncthreads();

    const int n_lo = upper_bound_i(offs, N, p0) - 1;
    const int n_hi = upper_bound_i(offs, N, p0 + cnt - 1) - 1;
    const int col = t & 63;
    const int grp = t >> 6;          // 4 groups
    const int pend = p0 + cnt;
    const int q = col >> 1;
    const bool hiHalf = (col & 1) != 0;

    for (int n = n_lo + grp; n <= n_hi; n += 4) {
        int lo = offs[n];
        int hi = lo + ideg[n];
        lo = lo > p0 ? lo : p0;
        hi = hi < pend ? hi : pend;
        if (lo >= hi) continue;
        float acc = 0.0f;
        for (int p = lo; p < hi; ++p) {
            const int sl = p - p0;
            const __half2 hv = lds[sl * 32 + (q ^ (sl & 31))];
            const float2 f2 = __half22float2(hv);
            acc += hiHalf ? f2.y : f2.x;
        }
        atomicAdd(&agg[(size_t)n * 64 + col], acc);
    }
}

// ---------------- fallback path (verified round 1): atomic scatter ----------------

template<int LAYER>
__global__ void __launch_bounds__(256) edge_scatter_kernel(
    const float* __restrict__ dist, const float* __restrict__ eraw,
    const int* __restrict__ senders, const int* __restrict__ receivers,
    const float* __restrict__ nf0, const float* __restrict__ nf1, const float* __restrict__ nf2,
    const float* __restrict__ eWe1, const float* __restrict__ ebe1,
    const float* __restrict__ eWe2, const float* __restrict__ ebe2,
    const float* __restrict__ We0, const float* __restrict__ Ws0, const float* __restrict__ b0,
    const float* __restrict__ We1, const float* __restrict__ Ws1, const float* __restrict__ b1,
    const float* __restrict__ We2, const float* __restrict__ Ws2, const float* __restrict__ b2,
    float* __restrict__ agg, int E, int E2)
{
    const int e = blockIdx.x * blockDim.x + threadIdx.x;
    if (e >= E2) return;
    const int orig = (e < E) ? e : e - E;
    const int s = (e < E) ? senders[orig] : receivers[orig];
    const int r = (e < E) ? receivers[orig] : senders[orig];

    float a0[16];
    chain_ef0(orig, s, dist, eraw, eWe1, ebe1, eWe2, ebe2, We0, Ws0, b0, nf0, a0);

    if constexpr (LAYER == 0) {
        float* dst = agg + (size_t)r * 16;
#pragma unroll
        for (int j = 0; j < 16; ++j) atomicAdd(dst + j, a0[j]);
    } else {
        float a1[32];
        load_bias<32>(b1, a1);
        mm_acc<16, 32>(a0, We1, a1);
        {
            float x[32];
            load_row<32>(nf1 + (size_t)s * 32, x);
            mm_acc<32, 32>(x, Ws1, a1);
        }
        relu_v<32>(a1);

        if constexpr (LAYER == 1) {
            float* dst = agg + (size_t)r * 32;
#pragma unroll
            for (int j = 0; j < 32; ++j) atomicAdd(dst + j, a1[j]);
        } else {
            float a2[64];
            load_bias<64>(b2, a2);
            mm_acc<32, 64>(a1, We2, a2);
            {
                const float* xr = nf2 + (size_t)s * 64;
#pragma unroll
                for (int k4 = 0; k4 < 16; ++k4) {
                    float4 v = reinterpret_cast<const float4*>(xr)[k4];
                    const float vv[4] = {v.x, v.y, v.z, v.w};
#pragma unroll
                    for (int u = 0; u < 4; ++u) {
                        const float val = vv[u];
                        const int k = k4 * 4 + u;
#pragma unroll
                        for (int j = 0; j < 64; ++j) a2[j] = fmaf(val, Ws2[k * 64 + j], a2[j]);
                    }
                }
            }
            relu_v<64>(a2);
            float* dst = agg + (size_t)r * 64;
#pragma unroll
            for (int j = 0; j < 64; ++j) atomicAdd(dst + j, a2[j]);
        }
    }
}

// ---------------- launch ----------------

static inline size_t align_up(size_t x, size_t a) { return (x + a - 1) & ~(a - 1); }

extern "C" void kernel_launch(void* const* d_in, const int* in_sizes, int n_in,
                              void* d_out, int out_size, void* d_ws, size_t ws_size,
                              hipStream_t stream) {
    const float* node_raw  = (const float*)d_in[0];
    const float* edge_raw  = (const float*)d_in[1];
    const float* distances = (const float*)d_in[2];
    const int*   residues  = (const int*)d_in[3];
    const int*   senders   = (const int*)d_in[4];
    const int*   receivers = (const int*)d_in[5];
    const int*   gidx      = (const int*)d_in[6];
    const float* emb       = (const float*)d_in[7];
    const float* eWe1 = (const float*)d_in[8];  const float* ebe1 = (const float*)d_in[9];
    const float* eWe2 = (const float*)d_in[10]; const float* ebe2 = (const float*)d_in[11];
    const float* nWn1 = (const float*)d_in[12]; const float* nbn1 = (const float*)d_in[13];
    const float* nWn2 = (const float*)d_in[14]; const float* nbn2 = (const float*)d_in[15];
    const float* roWg = (const float*)d_in[16]; const float* robg = (const float*)d_in[17];
    const float* roWn = (const float*)d_in[18]; const float* robn = (const float*)d_in[19];
    const float* l0We = (const float*)d_in[20]; const float* l0Ws = (const float*)d_in[21];
    const float* l0be = (const float*)d_in[22]; const float* l0Wn = (const float*)d_in[23];
    const float* l0Wi = (const float*)d_in[24]; const float* l0bn = (const float*)d_in[25];
    const float* l1We = (const float*)d_in[26]; const float* l1Ws = (const float*)d_in[27];
    const float* l1be = (const float*)d_in[28]; const float* l1Wn = (const float*)d_in[29];
    const float* l1Wi = (const float*)d_in[30]; const float* l1bn = (const float*)d_in[31];
    const float* l2We = (const float*)d_in[32]; const float* l2Ws = (const float*)d_in[33];
    const float* l2be = (const float*)d_in[34]; const float* l2Wn = (const float*)d_in[35];
    const float* l2Wi = (const float*)d_in[36]; const float* l2bn = (const float*)d_in[37];

    const int N  = in_sizes[3];
    const int E  = in_sizes[2];
    const int G  = out_size - 2 * N;
    const int E2 = 2 * E;
    const int nb = (N + 255) / 256;

    const dim3 blk(256);
    const int nb_N  = (N + 255) / 256;
    const int nb_E  = (E + 255) / 256;
    const int nb_E2 = (E2 + 255) / 256;
    const int nlb64 = (N + 63) / 64;

    // ---- workspace layout: tier B ~168 MB (proven), tier A adds ef0h 76.8 MB ----
    char* base = (char*)d_ws;
    size_t off = 0;
    int* ideg   = (int*)(base + off); off += align_up((size_t)N * 4, 16);
    int* offs   = (int*)(base + off); off += align_up((size_t)N * 4, 16);
    int* cursor = (int*)(base + off); off += align_up((size_t)N * 4, 16);
    int* bsum   = (int*)(base + off); off += align_up((size_t)1024 * 4, 16);
    float* nf0 = (float*)(base + off); off += (size_t)N * 16 * 4;
    float* nf1 = (float*)(base + off); off += (size_t)N * 32 * 4;
    float* nf2 = (float*)(base + off); off += (size_t)N * 64 * 4;
    float* nf3 = (float*)(base + off); off += (size_t)N * 128 * 4;
    float* agg = (float*)(base + off); off += (size_t)N * 64 * 4;
    const size_t need_fallback = off;
    int2* perm2 = (int2*)(base + off); off += align_up((size_t)E2 * 8, 16);
    float* y0 = (float*)(base + off); off += (size_t)N * 16 * 4;
    __half* y1h = (__half*)(base + off); off += align_up((size_t)N * 32 * 2, 16);
    __half* y2h = (__half*)(base + off); off += align_up((size_t)N * 64 * 2, 16);
    const size_t need_fast = off;
    __half2* ef0h = nullptr;                          // tier A (graceful)
    const size_t need_encA = need_fast + align_up((size_t)E2 * 16, 16);
    if (ws_size >= need_encA) ef0h = (__half2*)(base + need_fast);

    const bool fast = (ws_size >= need_fast);
    (void)need_fallback;

    // ---- common prologue ----
    hipMemsetAsync(ideg, 0, (size_t)N * 4, stream);
    k_count<<<nb_E, blk, 0, stream>>>(senders, receivers, ideg, E);
    node_enc_kernel<<<nb_N, blk, 0, stream>>>(node_raw, residues, emb, nWn1, nbn1, nWn2, nbn2,
                                              l0Ws, l0be, nf0, fast ? y0 : nullptr, N);

    if (fast) {
        // CSR permutation (packed, receiver-sorted slots)
        k_blocksum<<<nb, blk, 0, stream>>>(ideg, bsum, N);
        k_scan_partials<<<1, 1024, 0, stream>>>(bsum, nb);
        k_blockscan<<<nb, blk, 0, stream>>>(ideg, bsum, offs, cursor, N);
        k_scatter<<<nb_E, blk, 0, stream>>>(senders, receivers, cursor, perm2, E);

        // ---- layer 0 (stages ef0h when tier A fits) ----
        hipMemsetAsync(agg, 0, (size_t)N * 16 * 4, stream);
        fused0_kernel<<<nb_E2, blk, 0, stream>>>(distances, edge_raw, perm2, y0,
            eWe1, ebe1, eWe2, ebe2, l0We, offs, ideg, agg, ef0h, N, E2);
        node_layer_v4<16, 16, 32><<<nlb64, blk, 0, stream>>>(nf0, agg, ideg, l0Wn, l0Wi, l0bn, nf1, N);
        y_kernel<32><<<nlb64, blk, 0, stream>>>(nf1, l1Ws, l1be, nullptr, y1h, N);

        // ---- layer 1 ----
        hipMemsetAsync(agg, 0, (size_t)N * 32 * 4, stream);
        fused1_kernel<<<nb_E2, blk, 0, stream>>>(distances, edge_raw, perm2,
            y0, (const __half2*)y1h, ef0h,
            eWe1, ebe1, eWe2, ebe2, l0We, l1We, offs, ideg, agg, N, E2);
        node_layer_v4<32, 32, 64><<<nlb64, blk, 0, stream>>>(nf1, agg, ideg, l1Wn, l1Wi, l1bn, nf2, N);
        y_kernel<64><<<nlb64, blk, 0, stream>>>(nf2, l2Ws, l2be, nullptr, y2h, N);

        // ---- layer 2 ----
        hipMemsetAsync(agg, 0, (size_t)N * 64 * 4, stream);
        fused2_kernel<<<nb_E2, blk, 0, stream>>>(distances, edge_raw, perm2,
            y0, (const __half2*)y1h, (const __half2*)y2h, ef0h,
            eWe1, ebe1, eWe2, ebe2, l0We, l1We, l2We, offs, ideg, agg, N, E2);
        node_layer_v4b<<<nlb64, blk, 0, stream>>>(nf2, agg, ideg, l2Wn, l2Wi, l2bn, nf3, N);
    } else {
        // verified scatter fallback
        hipMemsetAsync(agg, 0, (size_t)N * 16 * 4, stream);
        edge_scatter_kernel<0><<<nb_E2, blk, 0, stream>>>(distances, edge_raw, senders, receivers,
            nf0, nf0, nf0, eWe1, ebe1, eWe2, ebe2,
            l0We, l0Ws, l0be, l1We, l1Ws, l1be, l2We, l2Ws, l2be, agg, E, E2);
        node_layer_v4<16, 16, 32><<<nlb64, blk, 0, stream>>>(nf0, agg, ideg, l0Wn, l0Wi, l0bn, nf1, N);

        hipMemsetAsync(agg, 0, (size_t)N * 32 * 4, stream);
        edge_scatter_kernel<1><<<nb_E2, blk, 0, stream>>>(distances, edge_raw, senders, receivers,
            nf0, nf1, nf1, eWe1, ebe1, eWe2, ebe2,
            l0We, l0Ws, l0be, l1We, l1Ws, l1be, l2We, l2Ws, l2be, agg, E, E2);
        node_layer_v4<32, 32, 64><<<nlb64, blk, 0, stream>>>(nf1, agg, ideg, l1Wn, l1Wi, l1bn, nf2, N);

        hipMemsetAsync(agg, 0, (size_t)N * 64 * 4, stream);
        edge_scatter_kernel<2><<<nb_E2, blk, 0, stream>>>(distances, edge_raw, senders, receivers,
            nf0, nf1, nf2, eWe1, ebe1, eWe2, ebe2,
            l0We, l0Ws, l0be, l1We, l1Ws, l1be, l2We, l2Ws, l2be, agg, E, E2);
        node_layer_v4b<<<nlb64, blk, 0, stream>>>(nf2, agg, ideg, l2Wn, l2Wi, l2bn, nf3, N);
    }

    // ---- readout ----
    node_out_kernel<<<nb_N, blk, 0, stream>>>(nf3, roWn, robn, (float*)d_out, N);
    graph_out_kernel<<<G, blk, 0, stream>>>(nf3, gidx, roWg, robg, (float*)d_out + (size_t)2 * N, N);
}

// Round 19
// 953.946 us; speedup vs baseline: 1.0350x; 1.0350x over previous
//
#include <hip/hip_runtime.h>
#include <hip/hip_fp16.h>
#include <cstdint>
#include <cstddef>

// ---------------- helpers ----------------

__device__ __forceinline__ float sigmoidf_(float x) {
    return 1.0f / (1.0f + __expf(-x));
}

template<int OUT>
__device__ __forceinline__ void load_bias(const float* __restrict__ b, float* __restrict__ acc) {
#pragma unroll
    for (int j = 0; j < OUT; ++j) acc[j] = b[j];
}

template<int OUT>
__device__ __forceinline__ void relu_v(float* __restrict__ acc) {
#pragma unroll
    for (int j = 0; j < OUT; ++j) acc[j] = fmaxf(acc[j], 0.0f);
}

template<int IN, int OUT>
__device__ __forceinline__ void mm_acc(const float* __restrict__ x,
                                       const float* __restrict__ W,
                                       float* __restrict__ acc) {
#pragma unroll 4
    for (int k = 0; k < IN; ++k) {
        const float v = x[k];
#pragma unroll
        for (int j = 0; j < OUT; ++j) acc[j] = fmaf(v, W[k * OUT + j], acc[j]);
    }
}

template<int WIDTH>
__device__ __forceinline__ void load_row(const float* __restrict__ p, float* __restrict__ x) {
#pragma unroll
    for (int k4 = 0; k4 < WIDTH / 4; ++k4) {
        float4 v = reinterpret_cast<const float4*>(p)[k4];
        x[k4 * 4 + 0] = v.x; x[k4 * 4 + 1] = v.y;
        x[k4 * 4 + 2] = v.z; x[k4 * 4 + 3] = v.w;
    }
}

template<int PAIRS>
__device__ __forceinline__ void load_h2(const __half2* __restrict__ p, float* __restrict__ x) {
#pragma unroll
    for (int q = 0; q < PAIRS; ++q) {
        const float2 f = __half22float2(p[q]);
        x[2 * q] = f.x; x[2 * q + 1] = f.y;
    }
}

// edge encoder: rbf(16)+raw(2) -> 4 -> 8 (relu after each)
__device__ __forceinline__ void enc_edge(int orig,
                                         const float* __restrict__ dist,
                                         const float* __restrict__ eraw,
                                         const float* __restrict__ We1, const float* __restrict__ be1,
                                         const float* __restrict__ We2, const float* __restrict__ be2,
                                         float* __restrict__ out8) {
    float x[18];
    const float d = dist[orig];
#pragma unroll
    for (int i = 0; i < 16; ++i) {
        const float c = (float)i * (20.0f / 15.0f);
        const float t = d - c;
        x[i] = __expf(-t * t);
    }
    x[16] = eraw[(size_t)orig * 2 + 0];
    x[17] = eraw[(size_t)orig * 2 + 1];
    float h[4];
    load_bias<4>(be1, h);
    mm_acc<18, 4>(x, We1, h);
    relu_v<4>(h);
    load_bias<8>(be2, out8);
    mm_acc<4, 8>(h, We2, out8);
    relu_v<8>(out8);
}

// y-hoisted chain: a0 = relu(y0[s] + enc@We0)
__device__ __forceinline__ void chain_ef0_y(int orig, int s,
    const float* __restrict__ dist, const float* __restrict__ eraw,
    const float* __restrict__ eWe1, const float* __restrict__ ebe1,
    const float* __restrict__ eWe2, const float* __restrict__ ebe2,
    const float* __restrict__ We0,
    const float* __restrict__ y0, float* __restrict__ a0)
{
    load_row<16>(y0 + (size_t)s * 16, a0);   // issue gather early (includes b0)
    float enc[8];
    enc_edge(orig, dist, eraw, eWe1, ebe1, eWe2, ebe2, enc);
    mm_acc<8, 16>(enc, We0, a0);
    relu_v<16>(a0);
}

// old chain for fallback path (verified)
__device__ __forceinline__ void chain_ef0(int orig, int s,
    const float* __restrict__ dist, const float* __restrict__ eraw,
    const float* __restrict__ eWe1, const float* __restrict__ ebe1,
    const float* __restrict__ eWe2, const float* __restrict__ ebe2,
    const float* __restrict__ We0, const float* __restrict__ Ws0, const float* __restrict__ b0,
    const float* __restrict__ nf0, float* __restrict__ a0)
{
    float x0[16];
    load_row<16>(nf0 + (size_t)s * 16, x0);
    float enc[8];
    enc_edge(orig, dist, eraw, eWe1, ebe1, eWe2, ebe2, enc);
    load_bias<16>(b0, a0);
    mm_acc<8, 16>(enc, We0, a0);
    mm_acc<16, 16>(x0, Ws0, a0);
    relu_v<16>(a0);
}

__device__ __forceinline__ int lower_bound_i(const int* __restrict__ a, int n, int key) {
    int lo = 0, hi = n;
    while (lo < hi) {
        int mid = (lo + hi) >> 1;
        if (a[mid] < key) lo = mid + 1; else hi = mid;
    }
    return lo;
}

// first index with a[idx] > key
__device__ __forceinline__ int upper_bound_i(const int* __restrict__ a, int n, int key) {
    int lo = 0, hi = n;
    while (lo < hi) {
        int mid = (lo + hi) >> 1;
        if (a[mid] <= key) lo = mid + 1; else hi = mid;
    }
    return lo;
}

// ---------------- CSR build ----------------

__global__ void __launch_bounds__(256) k_count(
    const int* __restrict__ senders, const int* __restrict__ receivers,
    int* __restrict__ ideg, int E)
{
    const int e = blockIdx.x * blockDim.x + threadIdx.x;
    if (e >= E) return;
    atomicAdd(&ideg[receivers[e]], 1);
    atomicAdd(&ideg[senders[e]], 1);
}

__global__ void __launch_bounds__(256) k_blocksum(
    const int* __restrict__ ideg, int* __restrict__ bsum, int N)
{
    __shared__ int s[256];
    const int t = threadIdx.x;
    const int i = blockIdx.x * 256 + t;
    s[t] = (i < N) ? ideg[i] : 0;
    __syncthreads();
#pragma unroll
    for (int d = 128; d > 0; d >>= 1) {
        if (t < d) s[t] += s[t + d];
        __syncthreads();
    }
    if (t == 0) bsum[blockIdx.x] = s[0];
}

__global__ void __launch_bounds__(1024) k_scan_partials(int* __restrict__ bsum, int nb)
{
    __shared__ int s[1024];
    const int t = threadIdx.x;
    const int v = (t < nb) ? bsum[t] : 0;
    s[t] = v;
    __syncthreads();
    for (int d = 1; d < 1024; d <<= 1) {
        const int w = (t >= d) ? s[t - d] : 0;
        __syncthreads();
        s[t] += w;
        __syncthreads();
    }
    if (t < nb) bsum[t] = s[t] - v;   // exclusive
}

__global__ void __launch_bounds__(256) k_blockscan(
    const int* __restrict__ ideg, const int* __restrict__ bsum,
    int* __restrict__ offs, int* __restrict__ cursor, int N)
{
    __shared__ int s[256];
    const int t = threadIdx.x;
    const int i = blockIdx.x * 256 + t;
    const int v = (i < N) ? ideg[i] : 0;
    s[t] = v;
    __syncthreads();
    for (int d = 1; d < 256; d <<= 1) {
        const int w = (t >= d) ? s[t - d] : 0;
        __syncthreads();
        s[t] += w;
        __syncthreads();
    }
    if (i < N) {
        const int o = bsum[blockIdx.x] + s[t] - v;
        offs[i] = o;
        cursor[i] = o;
    }
}

// packed: slot -> {orig edge, sender node} in one 8B store
__global__ void __launch_bounds__(256) k_scatter(
    const int* __restrict__ senders, const int* __restrict__ receivers,
    int* __restrict__ cursor, int2* __restrict__ perm2, int E)
{
    const int e = blockIdx.x * blockDim.x + threadIdx.x;
    if (e >= E) return;
    const int se = senders[e];
    const int re = receivers[e];
    const int p = atomicAdd(&cursor[re], 1);
    perm2[p] = make_int2(e, se);
    const int q = atomicAdd(&cursor[se], 1);
    perm2[q] = make_int2(e, re);
}

// per-original-edge encoder staging: enc8 -> fp16 (coalesced)
__global__ void __launch_bounds__(256) k_enc(
    const float* __restrict__ dist, const float* __restrict__ eraw,
    const float* __restrict__ eWe1, const float* __restrict__ ebe1,
    const float* __restrict__ eWe2, const float* __restrict__ ebe2,
    __half2* __restrict__ ench, int E)
{
    const int e = blockIdx.x * blockDim.x + threadIdx.x;
    if (e >= E) return;
    float enc[8];
    enc_edge(e, dist, eraw, eWe1, ebe1, eWe2, ebe2, enc);
    __half2* p = ench + (size_t)e * 4;
#pragma unroll
    for (int q = 0; q < 4; ++q)
        p[q] = __floats2half2_rn(enc[2 * q], enc[2 * q + 1]);
}

// ---------------- node-side kernels ----------------

__global__ void __launch_bounds__(256) node_enc_kernel(
    const float* __restrict__ node_raw, const int* __restrict__ residues,
    const float* __restrict__ emb,
    const float* __restrict__ Wn1, const float* __restrict__ bn1,
    const float* __restrict__ Wn2, const float* __restrict__ bn2,
    const float* __restrict__ Ws0, const float* __restrict__ b0,
    float* __restrict__ nf0, float* __restrict__ y0, __half* __restrict__ y0h, int N)
{
    __shared__ float raw[256 * 51];
    const int t = threadIdx.x;
    const int n0 = blockIdx.x * 256;
    int cnt = N - n0; if (cnt > 256) cnt = 256;
    const int tot = cnt * 51;
    for (int i = t; i < tot; i += 256)
        raw[i] = node_raw[(size_t)n0 * 51 + i];
    __syncthreads();

    const int n = n0 + t;
    if (n >= N) return;
    float h[8];
    load_bias<8>(bn1, h);
    {
        const float* er = emb + (size_t)residues[n] * 32;
        float x[32];
        load_row<32>(er, x);
        mm_acc<32, 8>(x, Wn1, h);
    }
    {
        const float* nr = &raw[t * 51];
#pragma unroll 4
        for (int k = 0; k < 51; ++k) {
            const float v = nr[k];
#pragma unroll
            for (int j = 0; j < 8; ++j) h[j] = fmaf(v, Wn1[(32 + k) * 8 + j], h[j]);
        }
    }
    relu_v<8>(h);
    float o[16];
    load_bias<16>(bn2, o);
    mm_acc<8, 16>(h, Wn2, o);
    relu_v<16>(o);
    float* dst = nf0 + (size_t)n * 16;
#pragma unroll
    for (int j = 0; j < 16; ++j) dst[j] = o[j];
    if (y0) {
        float yr[16];
        load_bias<16>(b0, yr);
        mm_acc<16, 16>(o, Ws0, yr);
        float* yd = y0 + (size_t)n * 16;
#pragma unroll
        for (int j = 0; j < 16; ++j) yd[j] = yr[j];
        if (y0h) {
            __half* yh = y0h + (size_t)n * 16;
#pragma unroll
            for (int j = 0; j < 16; ++j) yh[j] = __float2half(yr[j]);
        }
    }
}

// y[n][j] = b[j] + sum_k nf[n][k]*Ws[k][j] (IN==OUT); fp32 out + optional fp16 copy
template<int IN>
__global__ void __launch_bounds__(256) y_kernel(
    const float* __restrict__ nf, const float* __restrict__ Ws, const float* __restrict__ b,
    float* __restrict__ y, __half* __restrict__ yh, int N)
{
    constexpr int BN = 64;
    __shared__ float xs[BN * IN];
    const int t = threadIdx.x;
    const int n0 = blockIdx.x * BN;
    int cnt = N - n0; if (cnt > BN) cnt = BN;
    if (cnt <= 0) return;
    {
        const float4* gx = reinterpret_cast<const float4*>(nf + (size_t)n0 * IN);
        float4* lx = reinterpret_cast<float4*>(xs);
        const int nx = cnt * IN / 4;
        for (int i = t; i < nx; i += 256) lx[i] = gx[i];
    }
    __syncthreads();

    constexpr int SUB = 256 / IN;
    const int j = t % IN;
    const int m = t / IN;
    float w[IN];
#pragma unroll
    for (int k = 0; k < IN; ++k) w[k] = Ws[k * IN + j];
    const float bj = b[j];

    for (int nl = m; nl < cnt; nl += SUB) {
        const float4* x4 = reinterpret_cast<const float4*>(&xs[nl * IN]);
        float p0 = bj, p1 = 0.0f, p2 = 0.0f, p3 = 0.0f;
#pragma unroll
        for (int k4 = 0; k4 < IN / 4; ++k4) {
            float4 v = x4[k4];
            p0 = fmaf(v.x, w[4 * k4 + 0], p0);
            p1 = fmaf(v.y, w[4 * k4 + 1], p1);
            p2 = fmaf(v.z, w[4 * k4 + 2], p2);
            p3 = fmaf(v.w, w[4 * k4 + 3], p3);
        }
        const float r = (p0 + p1) + (p2 + p3);
        if (y)  y[(size_t)(n0 + nl) * IN + j] = r;
        if (yh) yh[(size_t)(n0 + nl) * IN + j] = __float2half(r);
    }
}

// LDS-tiled node layer (small)
template<int INN, int OE, int ON>
__global__ void __launch_bounds__(256) node_layer_v4(
    const float* __restrict__ nf_in, const float* __restrict__ agg, const int* __restrict__ ideg,
    const float* __restrict__ Wn, const float* __restrict__ Wi, const float* __restrict__ bn,
    float* __restrict__ nf_out, int N)
{
    constexpr int BN = 64;
    __shared__ float xs[BN * INN];
    __shared__ float as_[BN * OE];
    __shared__ float inv_s[BN];
    const int t = threadIdx.x;
    const int n0 = blockIdx.x * BN;
    int cnt = N - n0; if (cnt > BN) cnt = BN;
    if (cnt <= 0) return;

    {
        const float4* gx = reinterpret_cast<const float4*>(nf_in + (size_t)n0 * INN);
        float4* lx = reinterpret_cast<float4*>(xs);
        const int nx = cnt * INN / 4;
        for (int i = t; i < nx; i += 256) lx[i] = gx[i];
        const float4* ga = reinterpret_cast<const float4*>(agg + (size_t)n0 * OE);
        float4* la = reinterpret_cast<float4*>(as_);
        const int na = cnt * OE / 4;
        for (int i = t; i < na; i += 256) la[i] = ga[i];
        if (t < cnt) inv_s[t] = 1.0f / fmaxf((float)ideg[n0 + t], 1.0f);
    }
    __syncthreads();

    constexpr int SUB = 256 / ON;
    const int j = t % ON;
    const int m = t / ON;

    float wn[INN], wi[OE];
#pragma unroll
    for (int k = 0; k < INN; ++k) wn[k] = Wn[k * ON + j];
#pragma unroll
    for (int k = 0; k < OE; ++k)  wi[k] = Wi[k * ON + j];
    const float bj = bn[j];

    for (int nl = m; nl < cnt; nl += SUB) {
        const float4* x4 = reinterpret_cast<const float4*>(&xs[nl * INN]);
        const float4* a4 = reinterpret_cast<const float4*>(&as_[nl * OE]);
        const float inv = inv_s[nl];

        float p0 = bj, p1 = 0.0f, p2 = 0.0f, p3 = 0.0f;
#pragma unroll
        for (int k4 = 0; k4 < INN / 4; ++k4) {
            float4 v = x4[k4];
            p0 = fmaf(v.x, wn[4 * k4 + 0], p0);
            p1 = fmaf(v.y, wn[4 * k4 + 1], p1);
            p2 = fmaf(v.z, wn[4 * k4 + 2], p2);
            p3 = fmaf(v.w, wn[4 * k4 + 3], p3);
        }
        float q0 = 0.0f, q1 = 0.0f, q2 = 0.0f, q3 = 0.0f;
#pragma unroll
        for (int k4 = 0; k4 < OE / 4; ++k4) {
            float4 v = a4[k4];
            q0 = fmaf(v.x, wi[4 * k4 + 0], q0);
            q1 = fmaf(v.y, wi[4 * k4 + 1], q1);
            q2 = fmaf(v.z, wi[4 * k4 + 2], q2);
            q3 = fmaf(v.w, wi[4 * k4 + 3], q3);
        }
        const float r = (p0 + p1) + (p2 + p3) + inv * ((q0 + q1) + (q2 + q3));
        nf_out[(size_t)(n0 + nl) * ON + j] = fmaxf(r, 0.0f);
    }
}

// LDS-tiled split-k node layer for 64->128
__global__ void __launch_bounds__(256) node_layer_v4b(
    const float* __restrict__ nf_in, const float* __restrict__ agg, const int* __restrict__ ideg,
    const float* __restrict__ Wn, const float* __restrict__ Wi, const float* __restrict__ bn,
    float* __restrict__ nf_out, int N)
{
    constexpr int BN = 64;
    __shared__ float xs[BN * 64];
    __shared__ float as_[BN * 64];
    __shared__ float inv_s[BN];
    const int t = threadIdx.x;
    const int n0 = blockIdx.x * BN;
    int cnt = N - n0; if (cnt > BN) cnt = BN;
    if (cnt <= 0) return;

    {
        const float4* gx = reinterpret_cast<const float4*>(nf_in + (size_t)n0 * 64);
        float4* lx = reinterpret_cast<float4*>(xs);
        const int nx = cnt * 16;
        for (int i = t; i < nx; i += 256) lx[i] = gx[i];
        const float4* ga = reinterpret_cast<const float4*>(agg + (size_t)n0 * 64);
        float4* la = reinterpret_cast<float4*>(as_);
        for (int i = t; i < nx; i += 256) la[i] = ga[i];
        if (t < cnt) inv_s[t] = 1.0f / fmaxf((float)ideg[n0 + t], 1.0f);
    }
    __syncthreads();

    const int j = t >> 1;
    const int h = t & 1;

    float wn[32], wi[32];
#pragma unroll
    for (int k = 0; k < 32; ++k) wn[k] = Wn[(h * 32 + k) * 128 + j];
#pragma unroll
    for (int k = 0; k < 32; ++k) wi[k] = Wi[(h * 32 + k) * 128 + j];
    const float bj = bn[j];

    for (int nl = 0; nl < cnt; ++nl) {
        const float4* x4 = reinterpret_cast<const float4*>(&xs[nl * 64 + h * 32]);
        const float4* a4 = reinterpret_cast<const float4*>(&as_[nl * 64 + h * 32]);

        float p0 = 0.0f, p1 = 0.0f, p2 = 0.0f, p3 = 0.0f;
#pragma unroll
        for (int k4 = 0; k4 < 8; ++k4) {
            float4 v = x4[k4];
            p0 = fmaf(v.x, wn[4 * k4 + 0], p0);
            p1 = fmaf(v.y, wn[4 * k4 + 1], p1);
            p2 = fmaf(v.z, wn[4 * k4 + 2], p2);
            p3 = fmaf(v.w, wn[4 * k4 + 3], p3);
        }
        float q0 = 0.0f, q1 = 0.0f, q2 = 0.0f, q3 = 0.0f;
#pragma unroll
        for (int k4 = 0; k4 < 8; ++k4) {
            float4 v = a4[k4];
            q0 = fmaf(v.x, wi[4 * k4 + 0], q0);
            q1 = fmaf(v.y, wi[4 * k4 + 1], q1);
            q2 = fmaf(v.z, wi[4 * k4 + 2], q2);
            q3 = fmaf(v.w, wi[4 * k4 + 3], q3);
        }
        float r = (p0 + p1) + (p2 + p3) + inv_s[nl] * ((q0 + q1) + (q2 + q3));
        r += __shfl_xor(r, 1);
        if (h == 0)
            nf_out[(size_t)(n0 + nl) * 128 + j] = fmaxf(r + bj, 0.0f);
    }
}

__global__ void __launch_bounds__(256) node_out_kernel(
    const float* __restrict__ nf3,
    const float* __restrict__ roWn, const float* __restrict__ robn,
    float* __restrict__ node_out, int N)
{
    const int n = blockIdx.x * blockDim.x + threadIdx.x;
    if (n >= N) return;
    const float* x = nf3 + (size_t)n * 128;
    float a0 = robn[0], a1 = robn[1];
#pragma unroll 4
    for (int k4 = 0; k4 < 32; ++k4) {
        float4 v = reinterpret_cast<const float4*>(x)[k4];
        const float vv[4] = {v.x, v.y, v.z, v.w};
#pragma unroll
        for (int u = 0; u < 4; ++u) {
            const int k = k4 * 4 + u;
            a0 = fmaf(vv[u], roWn[k * 2 + 0], a0);
            a1 = fmaf(vv[u], roWn[k * 2 + 1], a1);
        }
    }
    node_out[(size_t)n * 2 + 0] = sigmoidf_(a0);
    node_out[(size_t)n * 2 + 1] = sigmoidf_(a1);
}

__global__ void __launch_bounds__(256) graph_out_kernel(
    const float* __restrict__ nf3, const int* __restrict__ gidx,
    const float* __restrict__ roWg, const float* __restrict__ robg,
    float* __restrict__ glob_out, int N)
{
    __shared__ float sred[256];
    __shared__ float gm[128];
    const int g = blockIdx.x;
    const int t = threadIdx.x;
    const int lo = lower_bound_i(gidx, N, g);
    const int hi = lower_bound_i(gidx, N, g + 1);
    const int cnt = hi - lo;

    const int c = t & 127;
    const int h = t >> 7;
    float acc = 0.0f;
    for (int i = lo + h; i < hi; i += 2)
        acc += nf3[(size_t)i * 128 + c];
    sred[t] = acc;
    __syncthreads();
    if (t < 128) {
        const float m = (sred[t] + sred[t + 128]) / fmaxf((float)cnt, 1.0f);
        gm[t] = m * roWg[t];
    }
    __syncthreads();
    if (t < 64) gm[t] += gm[t + 64];
    __syncthreads();
    if (t < 32) gm[t] += gm[t + 32];
    __syncthreads();
    if (t < 16) gm[t] += gm[t + 16];
    __syncthreads();
    if (t == 0) {
        float s = 0.0f;
#pragma unroll
        for (int i = 0; i < 16; ++i) s += gm[i];
        glob_out[g] = sigmoidf_(s + robg[0]);
    }
}

// ---------------- fused edge-transform + segmented aggregation ----------------

// layer 0: ef0[16], LDS row stride 17 (conflict-free). a0 from staged enc
// (fp16 gather) + y0h when available; stages ef0h for layers 1/2.
__global__ void __launch_bounds__(256) fused0_kernel(
    const float* __restrict__ dist, const float* __restrict__ eraw,
    const int2* __restrict__ perm2, const float* __restrict__ y0,
    const __half2* __restrict__ ench, const __half2* __restrict__ y0h,
    const float* __restrict__ eWe1, const float* __restrict__ ebe1,
    const float* __restrict__ eWe2, const float* __restrict__ ebe2,
    const float* __restrict__ We0,
    const int* __restrict__ offs, const int* __restrict__ ideg,
    float* __restrict__ agg, __half2* __restrict__ ef0h, int N, int E2)
{
    __shared__ float lds[256 * 17];
    const int t = threadIdx.x;
    const int p0 = blockIdx.x * 256;
    int cnt = E2 - p0; if (cnt > 256) cnt = 256;

    if (t < cnt) {
        const int2 pr = perm2[p0 + t];
        float a0[16];
        if (ench) {
            load_h2<8>(y0h + (size_t)pr.y * 8, a0);    // 32 B gather (includes b0)
            float enc[8];
            load_h2<4>(ench + (size_t)pr.x * 4, enc);  // 16 B gather
            mm_acc<8, 16>(enc, We0, a0);
            relu_v<16>(a0);
        } else {
            chain_ef0_y(pr.x, pr.y, dist, eraw, eWe1, ebe1, eWe2, ebe2, We0, y0, a0);
        }
        float* row = &lds[t * 17];
#pragma unroll
        for (int j = 0; j < 16; ++j) row[j] = a0[j];
        if (ef0h) {
            __half2* eh = ef0h + (size_t)(p0 + t) * 8;
#pragma unroll
            for (int q = 0; q < 8; ++q)
                eh[q] = __floats2half2_rn(a0[2 * q], a0[2 * q + 1]);
        }
    }
    __syncthreads();

    const int n_lo = upper_bound_i(offs, N, p0) - 1;
    const int n_hi = upper_bound_i(offs, N, p0 + cnt - 1) - 1;
    const int col = t & 15;
    const int grp = t >> 4;          // 16 groups
    const int pend = p0 + cnt;

    for (int n = n_lo + grp; n <= n_hi; n += 16) {
        int lo = offs[n];
        int hi = lo + ideg[n];
        lo = lo > p0 ? lo : p0;
        hi = hi < pend ? hi : pend;
        if (lo >= hi) continue;
        float acc = 0.0f;
        for (int p = lo; p < hi; ++p)
            acc += lds[(p - p0) * 17 + col];
        atomicAdd(&agg[(size_t)n * 16 + col], acc);
    }
}

// layer 1: ef1[32], stride-32 XOR swizzle. a0 from ef0h (linear fp16) when
// available, else chain recompute. y1 gathered as fp16.
__global__ void __launch_bounds__(256) fused1_kernel(
    const float* __restrict__ dist, const float* __restrict__ eraw,
    const int2* __restrict__ perm2,
    const float* __restrict__ y0, const __half2* __restrict__ y1h,
    const __half2* __restrict__ ef0h,
    const float* __restrict__ eWe1, const float* __restrict__ ebe1,
    const float* __restrict__ eWe2, const float* __restrict__ ebe2,
    const float* __restrict__ We0, const float* __restrict__ We1,
    const int* __restrict__ offs, const int* __restrict__ ideg,
    float* __restrict__ agg, int N, int E2)
{
    __shared__ float lds[256 * 32];   // 32 KB
    const int t = threadIdx.x;
    const int p0 = blockIdx.x * 256;
    int cnt = E2 - p0; if (cnt > 256) cnt = 256;

    if (t < cnt) {
        const int2 pr = perm2[p0 + t];
        const int s = pr.y;
        float a1[32];
        load_h2<16>(y1h + (size_t)s * 16, a1);     // 64 B gather (includes b1)
        float a0[16];
        if (ef0h) {
            load_h2<8>(ef0h + (size_t)(p0 + t) * 8, a0);   // linear 16 B
        } else {
            chain_ef0_y(pr.x, s, dist, eraw, eWe1, ebe1, eWe2, ebe2, We0, y0, a0);
        }
        mm_acc<16, 32>(a0, We1, a1);
        relu_v<32>(a1);
        const int m = t & 31;
        float* row = &lds[t * 32];
#pragma unroll
        for (int j = 0; j < 32; ++j) row[j ^ m] = a1[j];
    }
    __syncthreads();

    const int n_lo = upper_bound_i(offs, N, p0) - 1;
    const int n_hi = upper_bound_i(offs, N, p0 + cnt - 1) - 1;
    const int col = t & 31;
    const int grp = t >> 5;          // 8 groups
    const int pend = p0 + cnt;

    for (int n = n_lo + grp; n <= n_hi; n += 8) {
        int lo = offs[n];
        int hi = lo + ideg[n];
        lo = lo > p0 ? lo : p0;
        hi = hi < pend ? hi : pend;
        if (lo >= hi) continue;
        float acc = 0.0f;
        for (int p = lo; p < hi; ++p) {
            const int sl = p - p0;
            acc += lds[sl * 32 + (col ^ (sl & 31))];
        }
        atomicAdd(&agg[(size_t)n * 32 + col], acc);
    }
}

// layer 2: a0 from ef0h (linear) or chain; y1h/y2h fp16 gathers; ef2 in LDS
// fp16 pair-XOR swizzled. Phase B segmented sum.
__global__ void __launch_bounds__(256) fused2_kernel(
    const float* __restrict__ dist, const float* __restrict__ eraw,
    const int2* __restrict__ perm2,
    const float* __restrict__ y0, const __half2* __restrict__ y1h, const __half2* __restrict__ y2h,
    const __half2* __restrict__ ef0h,
    const float* __restrict__ eWe1, const float* __restrict__ ebe1,
    const float* __restrict__ eWe2, const float* __restrict__ ebe2,
    const float* __restrict__ We0, const float* __restrict__ We1, const float* __restrict__ We2,
    const int* __restrict__ offs, const int* __restrict__ ideg,
    float* __restrict__ agg, int N, int E2)
{
    __shared__ __half2 lds[256 * 32];   // 32 KB, 32 half2 words per slot
    const int t = threadIdx.x;
    const int p0 = blockIdx.x * 256;
    int cnt = E2 - p0; if (cnt > 256) cnt = 256;

    if (t < cnt) {
        const int2 pr = perm2[p0 + t];
        const int s = pr.y;
        // issue long-latency gathers first
        float a2[64];
        load_h2<32>(y2h + (size_t)s * 32, a2);     // 128 B gather (includes b2)
        float a1[32];
        load_h2<16>(y1h + (size_t)s * 16, a1);     // 64 B gather (includes b1)
        float a0[16];
        if (ef0h) {
            load_h2<8>(ef0h + (size_t)(p0 + t) * 8, a0);   // linear 16 B
        } else {
            chain_ef0_y(pr.x, s, dist, eraw, eWe1, ebe1, eWe2, ebe2, We0, y0, a0);
        }
        mm_acc<16, 32>(a0, We1, a1);
        relu_v<32>(a1);
        mm_acc<32, 64>(a1, We2, a2);                 // wave-uniform scalar We2
        const int m = t & 31;
        __half2* row = &lds[t * 32];
#pragma unroll
        for (int q = 0; q < 32; ++q) {
            row[q ^ m] = __floats2half2_rn(fmaxf(a2[2 * q], 0.0f),
                                           fmaxf(a2[2 * q + 1], 0.0f));
        }
    }
    __syncthreads();

    const int n_lo = upper_bound_i(offs, N, p0) - 1;
    const int n_hi = upper_bound_i(offs, N, p0 + cnt - 1) - 1;
    const int col = t & 63;
    const int grp = t >> 6;          // 4 groups
    const int pend = p0 + cnt;
    const int q = col >> 1;
    const bool hiHalf = (col & 1) != 0;

    for (int n = n_lo + grp; n <= n_hi; n += 4) {
        int lo = offs[n];
        int hi = lo + ideg[n];
        lo = lo > p0 ? lo : p0;
        hi = hi < pend ? hi : pend;
        if (lo >= hi) continue;
        float acc = 0.0f;
        for (int p = lo; p < hi; ++p) {
            const int sl = p - p0;
            const __half2 hv = lds[sl * 32 + (q ^ (sl & 31))];
            const float2 f2 = __half22float2(hv);
            acc += hiHalf ? f2.y : f2.x;
        }
        atomicAdd(&agg[(size_t)n * 64 + col], acc);
    }
}

// ---------------- fallback path (verified round 1): atomic scatter ----------------

template<int LAYER>
__global__ void __launch_bounds__(256) edge_scatter_kernel(
    const float* __restrict__ dist, const float* __restrict__ eraw,
    const int* __restrict__ senders, const int* __restrict__ receivers,
    const float* __restrict__ nf0, const float* __restrict__ nf1, const float* __restrict__ nf2,
    const float* __restrict__ eWe1, const float* __restrict__ ebe1,
    const float* __restrict__ eWe2, const float* __restrict__ ebe2,
    const float* __restrict__ We0, const float* __restrict__ Ws0, const float* __restrict__ b0,
    const float* __restrict__ We1, const float* __restrict__ Ws1, const float* __restrict__ b1,
    const float* __restrict__ We2, const float* __restrict__ Ws2, const float* __restrict__ b2,
    float* __restrict__ agg, int E, int E2)
{
    const int e = blockIdx.x * blockDim.x + threadIdx.x;
    if (e >= E2) return;
    const int orig = (e < E) ? e : e - E;
    const int s = (e < E) ? senders[orig] : receivers[orig];
    const int r = (e < E) ? receivers[orig] : senders[orig];

    float a0[16];
    chain_ef0(orig, s, dist, eraw, eWe1, ebe1, eWe2, ebe2, We0, Ws0, b0, nf0, a0);

    if constexpr (LAYER == 0) {
        float* dst = agg + (size_t)r * 16;
#pragma unroll
        for (int j = 0; j < 16; ++j) atomicAdd(dst + j, a0[j]);
    } else {
        float a1[32];
        load_bias<32>(b1, a1);
        mm_acc<16, 32>(a0, We1, a1);
        {
            float x[32];
            load_row<32>(nf1 + (size_t)s * 32, x);
            mm_acc<32, 32>(x, Ws1, a1);
        }
        relu_v<32>(a1);

        if constexpr (LAYER == 1) {
            float* dst = agg + (size_t)r * 32;
#pragma unroll
            for (int j = 0; j < 32; ++j) atomicAdd(dst + j, a1[j]);
        } else {
            float a2[64];
            load_bias<64>(b2, a2);
            mm_acc<32, 64>(a1, We2, a2);
            {
                const float* xr = nf2 + (size_t)s * 64;
#pragma unroll
                for (int k4 = 0; k4 < 16; ++k4) {
                    float4 v = reinterpret_cast<const float4*>(xr)[k4];
                    const float vv[4] = {v.x, v.y, v.z, v.w};
#pragma unroll
                    for (int u = 0; u < 4; ++u) {
                        const float val = vv[u];
                        const int k = k4 * 4 + u;
#pragma unroll
                        for (int j = 0; j < 64; ++j) a2[j] = fmaf(val, Ws2[k * 64 + j], a2[j]);
                    }
                }
            }
            relu_v<64>(a2);
            float* dst = agg + (size_t)r * 64;
#pragma unroll
            for (int j = 0; j < 64; ++j) atomicAdd(dst + j, a2[j]);
        }
    }
}

// ---------------- launch ----------------

static inline size_t align_up(size_t x, size_t a) { return (x + a - 1) & ~(a - 1); }

extern "C" void kernel_launch(void* const* d_in, const int* in_sizes, int n_in,
                              void* d_out, int out_size, void* d_ws, size_t ws_size,
                              hipStream_t stream) {
    const float* node_raw  = (const float*)d_in[0];
    const float* edge_raw  = (const float*)d_in[1];
    const float* distances = (const float*)d_in[2];
    const int*   residues  = (const int*)d_in[3];
    const int*   senders   = (const int*)d_in[4];
    const int*   receivers = (const int*)d_in[5];
    const int*   gidx      = (const int*)d_in[6];
    const float* emb       = (const float*)d_in[7];
    const float* eWe1 = (const float*)d_in[8];  const float* ebe1 = (const float*)d_in[9];
    const float* eWe2 = (const float*)d_in[10]; const float* ebe2 = (const float*)d_in[11];
    const float* nWn1 = (const float*)d_in[12]; const float* nbn1 = (const float*)d_in[13];
    const float* nWn2 = (const float*)d_in[14]; const float* nbn2 = (const float*)d_in[15];
    const float* roWg = (const float*)d_in[16]; const float* robg = (const float*)d_in[17];
    const float* roWn = (const float*)d_in[18]; const float* robn = (const float*)d_in[19];
    const float* l0We = (const float*)d_in[20]; const float* l0Ws = (const float*)d_in[21];
    const float* l0be = (const float*)d_in[22]; const float* l0Wn = (const float*)d_in[23];
    const float* l0Wi = (const float*)d_in[24]; const float* l0bn = (const float*)d_in[25];
    const float* l1We = (const float*)d_in[26]; const float* l1Ws = (const float*)d_in[27];
    const float* l1be = (const float*)d_in[28]; const float* l1Wn = (const float*)d_in[29];
    const float* l1Wi = (const float*)d_in[30]; const float* l1bn = (const float*)d_in[31];
    const float* l2We = (const float*)d_in[32]; const float* l2Ws = (const float*)d_in[33];
    const float* l2be = (const float*)d_in[34]; const float* l2Wn = (const float*)d_in[35];
    const float* l2Wi = (const float*)d_in[36]; const float* l2bn = (const float*)d_in[37];

    const int N  = in_sizes[3];
    const int E  = in_sizes[2];
    const int G  = out_size - 2 * N;
    const int E2 = 2 * E;
    const int nb = (N + 255) / 256;

    const dim3 blk(256);
    const int nb_N  = (N + 255) / 256;
    const int nb_E  = (E + 255) / 256;
    const int nb_E2 = (E2 + 255) / 256;
    const int nlb64 = (N + 63) / 64;

    // ---- workspace layout: tier B ~168 MB, tier A adds ef0h 76.8 MB (proven) ----
    char* base = (char*)d_ws;
    size_t off = 0;
    int* ideg   = (int*)(base + off); off += align_up((size_t)N * 4, 16);
    int* offs   = (int*)(base + off); off += align_up((size_t)N * 4, 16);
    int* cursor = (int*)(base + off); off += align_up((size_t)N * 4, 16);
    int* bsum   = (int*)(base + off); off += align_up((size_t)1024 * 4, 16);
    float* nf0 = (float*)(base + off); off += (size_t)N * 16 * 4;
    float* nf1 = (float*)(base + off); off += (size_t)N * 32 * 4;
    float* nf2 = (float*)(base + off); off += (size_t)N * 64 * 4;
    float* nf3 = (float*)(base + off); off += (size_t)N * 128 * 4;
    float* agg = (float*)(base + off); off += (size_t)N * 64 * 4;
    const size_t need_fallback = off;
    int2* perm2 = (int2*)(base + off); off += align_up((size_t)E2 * 8, 16);
    float* y0 = (float*)(base + off); off += (size_t)N * 16 * 4;
    __half* y1h = (__half*)(base + off); off += align_up((size_t)N * 32 * 2, 16);
    __half* y2h = (__half*)(base + off); off += align_up((size_t)N * 64 * 2, 16);
    const size_t need_fast = off;
    __half2* ef0h = nullptr;                          // tier A (graceful)
    const size_t need_encA = need_fast + align_up((size_t)E2 * 16, 16);
    if (ws_size >= need_encA) ef0h = (__half2*)(base + need_fast);

    const bool fast = (ws_size >= need_fast);
    (void)need_fallback;

    // enc/y0h staging aliased into nf3 (dead until node_layer_v4b) — zero footprint
    __half2* ench = nullptr;
    __half* y0h = nullptr;
    if (fast && (size_t)E * 16 + (size_t)N * 32 <= (size_t)N * 512) {
        ench = (__half2*)nf3;
        y0h = (__half*)((char*)nf3 + align_up((size_t)E * 16, 16));
    }

    // ---- common prologue ----
    hipMemsetAsync(ideg, 0, (size_t)N * 4, stream);
    k_count<<<nb_E, blk, 0, stream>>>(senders, receivers, ideg, E);
    node_enc_kernel<<<nb_N, blk, 0, stream>>>(node_raw, residues, emb, nWn1, nbn1, nWn2, nbn2,
                                              l0Ws, l0be, nf0, fast ? y0 : nullptr, y0h, N);

    if (fast) {
        // CSR permutation (packed, receiver-sorted slots)
        k_blocksum<<<nb, blk, 0, stream>>>(ideg, bsum, N);
        k_scan_partials<<<1, 1024, 0, stream>>>(bsum, nb);
        k_blockscan<<<nb, blk, 0, stream>>>(ideg, bsum, offs, cursor, N);
        k_scatter<<<nb_E, blk, 0, stream>>>(senders, receivers, cursor, perm2, E);
        if (ench)
            k_enc<<<nb_E, blk, 0, stream>>>(distances, edge_raw, eWe1, ebe1, eWe2, ebe2, ench, E);

        // ---- layer 0 (stages ef0h) ----
        hipMemsetAsync(agg, 0, (size_t)N * 16 * 4, stream);
        fused0_kernel<<<nb_E2, blk, 0, stream>>>(distances, edge_raw, perm2, y0,
            ench, (const __half2*)y0h,
            eWe1, ebe1, eWe2, ebe2, l0We, offs, ideg, agg, ef0h, N, E2);
        node_layer_v4<16, 16, 32><<<nlb64, blk, 0, stream>>>(nf0, agg, ideg, l0Wn, l0Wi, l0bn, nf1, N);
        y_kernel<32><<<nlb64, blk, 0, stream>>>(nf1, l1Ws, l1be, nullptr, y1h, N);

        // ---- layer 1 ----
        hipMemsetAsync(agg, 0, (size_t)N * 32 * 4, stream);
        fused1_kernel<<<nb_E2, blk, 0, stream>>>(distances, edge_raw, perm2,
            y0, (const __half2*)y1h, ef0h,
            eWe1, ebe1, eWe2, ebe2, l0We, l1We, offs, ideg, agg, N, E2);
        node_layer_v4<32, 32, 64><<<nlb64, blk, 0, stream>>>(nf1, agg, ideg, l1Wn, l1Wi, l1bn, nf2, N);
        y_kernel<64><<<nlb64, blk, 0, stream>>>(nf2, l2Ws, l2be, nullptr, y2h, N);

        // ---- layer 2 ----
        hipMemsetAsync(agg, 0, (size_t)N * 64 * 4, stream);
        fused2_kernel<<<nb_E2, blk, 0, stream>>>(distances, edge_raw, perm2,
            y0, (const __half2*)y1h, (const __half2*)y2h, ef0h,
            eWe1, ebe1, eWe2, ebe2, l0We, l1We, l2We, offs, ideg, agg, N, E2);
        node_layer_v4b<<<nlb64, blk, 0, stream>>>(nf2, agg, ideg, l2Wn, l2Wi, l2bn, nf3, N);
    } else {
        // verified scatter fallback
        hipMemsetAsync(agg, 0, (size_t)N * 16 * 4, stream);
        edge_scatter_kernel<0><<<nb_E2, blk, 0, stream>>>(distances, edge_raw, senders, receivers,
            nf0, nf0, nf0, eWe1, ebe1, eWe2, ebe2,
            l0We, l0Ws, l0be, l1We, l1Ws, l1be, l2We, l2Ws, l2be, agg, E, E2);
        node_layer_v4<16, 16, 32><<<nlb64, blk, 0, stream>>>(nf0, agg, ideg, l0Wn, l0Wi, l0bn, nf1, N);

        hipMemsetAsync(agg, 0, (size_t)N * 32 * 4, stream);
        edge_scatter_kernel<1><<<nb_E2, blk, 0, stream>>>(distances, edge_raw, senders, receivers,
            nf0, nf1, nf1, eWe1, ebe1, eWe2, ebe2,
            l0We, l0Ws, l0be, l1We, l1Ws, l1be, l2We, l2Ws, l2be, agg, E, E2);
        node_layer_v4<32, 32, 64><<<nlb64, blk, 0, stream>>>(nf1, agg, ideg, l1Wn, l1Wi, l1bn, nf2, N);

        hipMemsetAsync(agg, 0, (size_t)N * 64 * 4, stream);
        edge_scatter_kernel<2><<<nb_E2, blk, 0, stream>>>(distances, edge_raw, senders, receivers,
            nf0, nf1, nf2, eWe1, ebe1, eWe2, ebe2,
            l0We, l0Ws, l0be, l1We, l1Ws, l1be, l2We, l2Ws, l2be, agg, E, E2);
        node_layer_v4b<<<nlb64, blk, 0, stream>>>(nf2, agg, ideg, l2Wn, l2Wi, l2bn, nf3, N);
    }

    // ---- readout ----
    node_out_kernel<<<nb_N, blk, 0, stream>>>(nf3, roWn, robn, (float*)d_out, N);
    graph_out_kernel<<<G, blk, 0, stream>>>(nf3, gidx, roWg, robg, (float*)d_out + (size_t)2 * N, N);
}